// Round 1
// 1108.229 us; speedup vs baseline: 1.0553x; 1.0553x over previous
//
#include <hip/hip_runtime.h>
#include <stdint.h>

// ---------------------------------------------------------------------------
// out = x @ nf4_quant_dequant(w).T
//   x: [M=16384, K=4096] fp32,  w: [N=4096, K=4096] fp32,  out: [M, N] fp32
// Plan: (1) fake-quant w -> bf16 in ws, (2) cast x -> bf16 in ws,
//       (3) bf16 MFMA GEMM (256x256 8-phase counted-vmcnt template:
//           T1 XCD swizzle + T2 LDS XOR swizzle + T3/T4 8-phase + T5 setprio).
// ws usage: w_bf16 (33.5 MB) + x_bf16 (134 MB) = 168 MB.
// ---------------------------------------------------------------------------

typedef __bf16 bf16x8 __attribute__((ext_vector_type(8)));
typedef float f32x4 __attribute__((ext_vector_type(4)));

// NF4 codebook (exact fp32 values) + midpoint boundaries (compile-time fp32).
constexpr float NF4_CODE[16] = {
    -1.0f, -0.6961928009986877f, -0.5250730514526367f, -0.39491748809814453f,
    -0.28444138169288635f, -0.18477343022823334f, -0.09105003625154495f, 0.0f,
    0.07958029955625534f, 0.16093020141124725f, 0.24611230194568634f,
    0.33791524171829224f, 0.44070982933044434f, 0.5626170039176941f,
    0.7229568362236023f, 1.0f};
constexpr float NF4_BND[15] = {
    0.5f * (NF4_CODE[0] + NF4_CODE[1]),   0.5f * (NF4_CODE[1] + NF4_CODE[2]),
    0.5f * (NF4_CODE[2] + NF4_CODE[3]),   0.5f * (NF4_CODE[3] + NF4_CODE[4]),
    0.5f * (NF4_CODE[4] + NF4_CODE[5]),   0.5f * (NF4_CODE[5] + NF4_CODE[6]),
    0.5f * (NF4_CODE[6] + NF4_CODE[7]),   0.5f * (NF4_CODE[7] + NF4_CODE[8]),
    0.5f * (NF4_CODE[8] + NF4_CODE[9]),   0.5f * (NF4_CODE[9] + NF4_CODE[10]),
    0.5f * (NF4_CODE[10] + NF4_CODE[11]), 0.5f * (NF4_CODE[11] + NF4_CODE[12]),
    0.5f * (NF4_CODE[12] + NF4_CODE[13]), 0.5f * (NF4_CODE[13] + NF4_CODE[14]),
    0.5f * (NF4_CODE[14] + NF4_CODE[15])};

__device__ __forceinline__ unsigned short f2bf(float f) {
  // RNE fp32 -> bf16 (inputs are finite; no NaN handling needed)
  unsigned int u = __float_as_uint(f);
  u += 0x7fffu + ((u >> 16) & 1u);
  return (unsigned short)(u >> 16);
}

// ---------------------------------------------------------------------------
// Kernel 1: NF4 fake quant-dequant of weights, fp32 -> bf16 bits.
// ---------------------------------------------------------------------------
__global__ __launch_bounds__(256) void nf4_dequant(const float* __restrict__ w,
                                                   unsigned short* __restrict__ wdq) {
  __shared__ float s_am[256];
  __shared__ float s_code[16];
  const int t = threadIdx.x;
  if (t < 16) s_code[t] = NF4_CODE[t];

  const size_t base = (size_t)blockIdx.x * 16384 + (size_t)t * 64;
  const float4* src = (const float4*)(w + base);
  float4 v[16];
  float amax = 0.f;
#pragma unroll
  for (int i = 0; i < 16; ++i) {
    v[i] = src[i];
    amax = fmaxf(amax, fmaxf(fmaxf(fabsf(v[i].x), fabsf(v[i].y)),
                             fmaxf(fabsf(v[i].z), fabsf(v[i].w))));
  }
  s_am[t] = amax;
  __syncthreads();
#pragma unroll
  for (int off = 128; off > 0; off >>= 1) {
    if (t < off) s_am[t] = fmaxf(s_am[t], s_am[t + off]);
    __syncthreads();
  }
  const float s_amax = s_am[0];
  const float sa = (s_amax == 0.f) ? 1.f : s_amax;
  float q8 = rintf(amax / sa * 127.f);
  q8 = fminf(fmaxf(q8, -127.f), 127.f);
  const float scale = (q8 / 127.f) * sa;
  const float safe_am = (amax == 0.f) ? 1.f : amax;

  auto dq1 = [&](float x) -> unsigned short {
    const float norm = x / safe_am;
    int idx = 0;
#pragma unroll
    for (int j = 0; j < 15; ++j) idx += (NF4_BND[j] < norm) ? 1 : 0;
    return f2bf(s_code[idx] * scale);
  };

  uint4* dst = (uint4*)(wdq + base);
#pragma unroll
  for (int i = 0; i < 8; ++i) {
    const float4 a = v[2 * i], b = v[2 * i + 1];
    uint4 o;
    o.x = (unsigned)dq1(a.x) | ((unsigned)dq1(a.y) << 16);
    o.y = (unsigned)dq1(a.z) | ((unsigned)dq1(a.w) << 16);
    o.z = (unsigned)dq1(b.x) | ((unsigned)dq1(b.y) << 16);
    o.w = (unsigned)dq1(b.z) | ((unsigned)dq1(b.w) << 16);
    dst[i] = o;
  }
}

// ---------------------------------------------------------------------------
// Kernel 2: cast x fp32 -> bf16 bits
// ---------------------------------------------------------------------------
__global__ __launch_bounds__(256) void cast_f32_to_bf16(const float* __restrict__ x,
                                                        unsigned short* __restrict__ y,
                                                        size_t n8) {
  const size_t i = (size_t)blockIdx.x * 256 + threadIdx.x;
  if (i >= n8) return;
  const float4* s = (const float4*)x + i * 2;
  const float4 a = s[0], b = s[1];
  uint4 o;
  o.x = (unsigned)f2bf(a.x) | ((unsigned)f2bf(a.y) << 16);
  o.y = (unsigned)f2bf(a.z) | ((unsigned)f2bf(a.w) << 16);
  o.z = (unsigned)f2bf(b.x) | ((unsigned)f2bf(b.y) << 16);
  o.w = (unsigned)f2bf(b.z) | ((unsigned)f2bf(b.w) << 16);
  ((uint4*)y)[i] = o;
}

// ---------------------------------------------------------------------------
// Kernel 3: C[M,N] = A[M,K] * Bt[N,K]^T, bf16 inputs, fp32 out.
// 256x256 tile, BK=64, 512 threads (8 waves = 2Mx4N, each wave 128x64 via
// 8x4 grid of v_mfma_f32_16x16x32_bf16). 8-phase schedule, 2 K-tiles/iter,
// counted vmcnt(4) at phases 4/8 only, s_setprio around MFMA clusters.
//
// LDS (128 KiB): [buf(2)][A/B(2)][half(2)][128 rows][64 k] bf16.
// T2 swizzle: within a row (8 x 16B chunks), chunk slot s at row r holds
// logical k-chunk s ^ (r&7).  global_load_lds writes linearly (lane -> chunk
// wave*64+lane resp. 512+...), so the SOURCE global address is pre-swizzled
// (j = (lane&7) ^ (lane>>3)); ds_read applies the same XOR (involution).
//
// Race-freedom: all ds_reads of a buffer are confined to 2 phases; the
// prefetch overwriting that buffer is issued only after those reads' lgkm0 +
// barrier (WAR), and vmcnt(4) at P4/P8 + barrier guarantees a tile is fully
// landed before the phase pair that reads it (RAW):
//  P1: rd buf0(Alo,Blo) | stg B0(t+1)->buf1 | bar lgkm0 mfma(q00,buf0) bar
//  P2: rd buf0(Ahi,Bhi) | stg B1(t+1)->buf1 | bar lgkm0 mfma(q01) bar
//  P3:                    stg A0(t+2)->buf0 | bar       mfma(q10) bar
//  P4:                    stg A1(t+2)->buf0 | vmcnt(4) bar mfma(q11) bar
//  P5: rd buf1(Alo,Blo) | stg B0(t+2)->buf0 | bar lgkm0 mfma(q00,buf1) bar
//  P6: rd buf1(Ahi,Bhi) | stg B1(t+2)->buf0 | bar lgkm0 mfma(q01) bar
//  P7:                    stg A0(t+3)->buf1 | bar       mfma(q10) bar
//  P8:                    stg A1(t+3)->buf1 | vmcnt(4) bar mfma(q11) bar
// ---------------------------------------------------------------------------

__device__ __forceinline__ void gld16(const unsigned short* g, unsigned short* l) {
  __builtin_amdgcn_global_load_lds(
      (__attribute__((address_space(1))) void*)g,
      (__attribute__((address_space(3))) void*)l, 16, 0, 0);
}

#define BAR __builtin_amdgcn_s_barrier()
#define LGKM0 asm volatile("s_waitcnt lgkmcnt(0)" ::: "memory")
#define VMW(n) asm volatile("s_waitcnt vmcnt(" #n ")" ::: "memory")

#define STG(buf, ab, hf, ks)                                                   \
  do {                                                                         \
    const unsigned short* g_ =                                                 \
        ((ab) ? gB0 : gA0) + (size_t)(hf)*HOFF + (size_t)(ks);                 \
    unsigned short* l_ =                                                       \
        lds + (buf)*32768 + (ab)*16384 + (hf)*8192 + wvoff;                    \
    gld16(g_, l_);                                                             \
    gld16(g_ + 64 * (size_t)K, l_ + 4096);                                     \
  } while (0)

#define RDA(buf, hi)                                                           \
  do {                                                                         \
    _Pragma("unroll") for (int i4 = 0; i4 < 4; ++i4) {                         \
      afr[(hi)*4 + i4][0] = *(const bf16x8*)(pa + (buf)*32768 +                \
                                             ((hi)*4 + i4) * 1024 + aoff0);    \
      afr[(hi)*4 + i4][1] = *(const bf16x8*)(pa + (buf)*32768 +                \
                                             ((hi)*4 + i4) * 1024 + aoff1);    \
    }                                                                          \
  } while (0)

#define RDB(buf, hi)                                                           \
  do {                                                                         \
    _Pragma("unroll") for (int j2 = 0; j2 < 2; ++j2) {                         \
      bfr[(hi)*2 + j2][0] = *(const bf16x8*)(pb + (buf)*32768 +                \
                                             ((hi)*2 + j2) * 1024 + aoff0);    \
      bfr[(hi)*2 + j2][1] = *(const bf16x8*)(pb + (buf)*32768 +                \
                                             ((hi)*2 + j2) * 1024 + aoff1);    \
    }                                                                          \
  } while (0)

#define MM(mh, nh)                                                             \
  do {                                                                         \
    __builtin_amdgcn_s_setprio(1);                                             \
    _Pragma("unroll") for (int ks = 0; ks < 2; ++ks) {                         \
      _Pragma("unroll") for (int i4 = 0; i4 < 4; ++i4) {                       \
        _Pragma("unroll") for (int j2 = 0; j2 < 2; ++j2) {                     \
          acc[(mh)*4 + i4][(nh)*2 + j2] =                                      \
              __builtin_amdgcn_mfma_f32_16x16x32_bf16(                         \
                  afr[(mh)*4 + i4][ks], bfr[(nh)*2 + j2][ks],                  \
                  acc[(mh)*4 + i4][(nh)*2 + j2], 0, 0, 0);                     \
        }                                                                      \
      }                                                                        \
    }                                                                          \
    __builtin_amdgcn_s_setprio(0);                                             \
  } while (0)

__global__ __launch_bounds__(512, 2) void gemm8p(const unsigned short* __restrict__ A,
                                                 const unsigned short* __restrict__ Bt,
                                                 float* __restrict__ C,
                                                 int M, int N, int K) {
  __shared__ __align__(16) unsigned short lds[65536];  // 128 KiB

  const int t = threadIdx.x;
  const int wave = t >> 6;
  const int lane = t & 63;

  // --- T1: bijective XCD-aware block swizzle ---
  const int nbx = N >> 8;
  const int nwg = nbx * (M >> 8);
  const int q8 = nwg >> 3, r8 = nwg & 7;
  const int xcd = (int)blockIdx.x & 7, off = (int)blockIdx.x >> 3;
  const int wg =
      (xcd < r8 ? xcd * (q8 + 1) : r8 * (q8 + 1) + (xcd - r8) * q8) + off;
  const int bm = (wg / nbx) << 8;
  const int bn = (wg % nbx) << 8;

  // --- staging addressing (per-lane, source pre-swizzled) ---
  const size_t HOFF = (size_t)128 * K;            // half-tile row offset (elems)
  const int srow = wave * 8 + (lane >> 3);        // q0 local row in [0,64)
  const int sj = (lane & 7) ^ (lane >> 3);        // inverse-swizzled k-chunk
  const unsigned short* gA0 = A + (size_t)(bm + srow) * K + sj * 8;
  const unsigned short* gB0 = Bt + (size_t)(bn + srow) * K + sj * 8;
  const int wvoff = wave * 512;                   // LDS chunk base (elems)

  // --- compute addressing ---
  const int wm = wave >> 2;   // m half owned by this wave (A half)
  const int wn = wave & 3;    // n quarter owned by this wave
  const int quad = lane >> 4;
  const int lrow = lane & 15;
  const int s0 = quad ^ (lrow & 7);               // swizzled chunk, ks=0
  const int aoff0 = lrow * 64 + s0 * 8;           // elems within half-region
  const int aoff1 = lrow * 64 + (s0 ^ 4) * 8;     // ks=1
  const unsigned short* pa = lds + wm * 8192;
  const unsigned short* pb = lds + 16384 + (wn >> 1) * 8192 + (wn & 1) * 4096;

  f32x4 acc[8][4];
  const f32x4 zero = {0.f, 0.f, 0.f, 0.f};
#pragma unroll
  for (int i = 0; i < 8; ++i)
#pragma unroll
    for (int j = 0; j < 4; ++j) acc[i][j] = zero;

  bf16x8 afr[8][2];
  bf16x8 bfr[4][2];

  // --- prologue: tile0 (A+B) -> buf0, tile1 A halves -> buf1 ---
  STG(0, 0, 0, 0);
  STG(0, 0, 1, 0);
  STG(0, 1, 0, 0);
  STG(0, 1, 1, 0);
  STG(1, 0, 0, 64);
  STG(1, 0, 1, 64);
  VMW(4);  // tile0 fully landed (tile1 A halves may still fly)
  BAR;

  const int niter = K >> 7;  // 2 K-tiles (2*BK=128) per iteration
  for (int it = 0; it < niter; ++it) {
    const int kt = it << 7;
    const int kS1 = kt + 64;
    int kS2 = kt + 128; if (kS2 > K - 64) kS2 = K - 64;  // clamp: last-iter
    int kS3 = kt + 192; if (kS3 > K - 64) kS3 = K - 64;  // stages are unread

    // P1
    RDA(0, 0); RDB(0, 0); STG(1, 1, 0, kS1);
    BAR; LGKM0; MM(0, 0); BAR;
    // P2
    RDA(0, 1); RDB(0, 1); STG(1, 1, 1, kS1);
    BAR; LGKM0; MM(0, 1); BAR;
    // P3
    STG(0, 0, 0, kS2);
    BAR; MM(1, 0); BAR;
    // P4
    STG(0, 0, 1, kS2); VMW(4);
    BAR; MM(1, 1); BAR;
    // P5
    RDA(1, 0); RDB(1, 0); STG(0, 1, 0, kS2);
    BAR; LGKM0; MM(0, 0); BAR;
    // P6
    RDA(1, 1); RDB(1, 1); STG(0, 1, 1, kS2);
    BAR; LGKM0; MM(0, 1); BAR;
    // P7
    STG(1, 0, 0, kS3);
    BAR; MM(1, 0); BAR;
    // P8
    STG(1, 0, 1, kS3); VMW(4);
    BAR; MM(1, 1); BAR;
  }

  // drain LDS-DMA before epilogue / block exit
  VMW(0);
  BAR;

  // epilogue: D[row=quad*4+r][col=lrow] per 16x16 tile
  const int crow = bm + wm * 128 + quad * 4;
  const int ccol = bn + wn * 64 + lrow;
#pragma unroll
  for (int i = 0; i < 8; ++i) {
#pragma unroll
    for (int j = 0; j < 4; ++j) {
      float* cp = C + (size_t)(crow + i * 16) * N + (ccol + j * 16);
#pragma unroll
      for (int r = 0; r < 4; ++r) cp[(size_t)r * N] = acc[i][j][r];
    }
  }
}

// ---------------------------------------------------------------------------
extern "C" void kernel_launch(void* const* d_in, const int* in_sizes, int n_in,
                              void* d_out, int out_size, void* d_ws, size_t ws_size,
                              hipStream_t stream) {
  const float* x = (const float*)d_in[0];   // [M, K]
  const float* w = (const float*)d_in[1];   // [N, K]
  const int K = 4096;
  const int M = in_sizes[0] / K;            // 16384
  const int N = in_sizes[1] / K;            // 4096

  unsigned short* wdq = (unsigned short*)d_ws;            // [N*K] bf16 bits
  unsigned short* xbf = wdq + (size_t)in_sizes[1];        // [M*K] bf16 bits
  // needs ws_size >= 2*(in_sizes[0]+in_sizes[1]) = 168 MB

  nf4_dequant<<<in_sizes[1] / 16384, 256, 0, stream>>>(w, wdq);
  cast_f32_to_bf16<<<((size_t)in_sizes[0] / 8 + 255) / 256, 256, 0, stream>>>(
      x, xbf, (size_t)in_sizes[0] / 8);
  dim3 grid((N / 256) * (M / 256));
  gemm8p<<<grid, 512, 0, stream>>>(xbf, wdq, (float*)d_out, M, N, K);
}

// Round 3
// 887.547 us; speedup vs baseline: 1.3177x; 1.2486x over previous
//
#include <hip/hip_runtime.h>
#include <stdint.h>

// ---------------------------------------------------------------------------
// out = x @ nf4_quant_dequant(w).T
//   x: [M=16384, K=4096] fp32,  w: [N=4096, K=4096] fp32,  out: [M, N] fp32
// Plan: (1) fake-quant w -> bf16 in ws, (2) cast x -> bf16 in ws,
//       (3) bf16 MFMA GEMM: 256x256 tile, BK=64, 8 waves, 8-phase schedule
//           with UNIFORM 4-7 phase prefetch distance and vmcnt(6) waits
//           (T1 XCD swizzle + T2 LDS XOR swizzle + T3/T4 + T5 setprio),
//           nontemporal C stores (keep A/B panels resident in L3).
// ws usage: w_bf16 (33.5 MB) + x_bf16 (134 MB) = 168 MB.
// ---------------------------------------------------------------------------

typedef __bf16 bf16x8 __attribute__((ext_vector_type(8)));
typedef float f32x4 __attribute__((ext_vector_type(4)));  // native vec (nt-load OK)

constexpr float NF4_CODE[16] = {
    -1.0f, -0.6961928009986877f, -0.5250730514526367f, -0.39491748809814453f,
    -0.28444138169288635f, -0.18477343022823334f, -0.09105003625154495f, 0.0f,
    0.07958029955625534f, 0.16093020141124725f, 0.24611230194568634f,
    0.33791524171829224f, 0.44070982933044434f, 0.5626170039176941f,
    0.7229568362236023f, 1.0f};
constexpr float NF4_BND[15] = {
    0.5f * (NF4_CODE[0] + NF4_CODE[1]),   0.5f * (NF4_CODE[1] + NF4_CODE[2]),
    0.5f * (NF4_CODE[2] + NF4_CODE[3]),   0.5f * (NF4_CODE[3] + NF4_CODE[4]),
    0.5f * (NF4_CODE[4] + NF4_CODE[5]),   0.5f * (NF4_CODE[5] + NF4_CODE[6]),
    0.5f * (NF4_CODE[6] + NF4_CODE[7]),   0.5f * (NF4_CODE[7] + NF4_CODE[8]),
    0.5f * (NF4_CODE[8] + NF4_CODE[9]),   0.5f * (NF4_CODE[9] + NF4_CODE[10]),
    0.5f * (NF4_CODE[10] + NF4_CODE[11]), 0.5f * (NF4_CODE[11] + NF4_CODE[12]),
    0.5f * (NF4_CODE[12] + NF4_CODE[13]), 0.5f * (NF4_CODE[13] + NF4_CODE[14]),
    0.5f * (NF4_CODE[14] + NF4_CODE[15])};

__device__ __forceinline__ unsigned short f2bf(float f) {
  unsigned int u = __float_as_uint(f);
  u += 0x7fffu + ((u >> 16) & 1u);
  return (unsigned short)(u >> 16);
}

// ---------------------------------------------------------------------------
// Kernel 1: NF4 fake quant-dequant of weights, fp32 -> bf16 bits.
// ---------------------------------------------------------------------------
__global__ __launch_bounds__(256) void nf4_dequant(const float* __restrict__ w,
                                                   unsigned short* __restrict__ wdq) {
  __shared__ float s_am[256];
  __shared__ float s_code[16];
  const int t = threadIdx.x;
  if (t < 16) s_code[t] = NF4_CODE[t];

  const size_t base = (size_t)blockIdx.x * 16384 + (size_t)t * 64;
  const f32x4* src = (const f32x4*)(w + base);
  f32x4 v[16];
  float amax = 0.f;
#pragma unroll
  for (int i = 0; i < 16; ++i) {
    v[i] = __builtin_nontemporal_load(src + i);  // w never re-read: keep L3 clean
    amax = fmaxf(amax, fmaxf(fmaxf(fabsf(v[i][0]), fabsf(v[i][1])),
                             fmaxf(fabsf(v[i][2]), fabsf(v[i][3]))));
  }
  s_am[t] = amax;
  __syncthreads();
#pragma unroll
  for (int off = 128; off > 0; off >>= 1) {
    if (t < off) s_am[t] = fmaxf(s_am[t], s_am[t + off]);
    __syncthreads();
  }
  const float s_amax = s_am[0];
  const float sa = (s_amax == 0.f) ? 1.f : s_amax;
  float q8 = rintf(amax / sa * 127.f);
  q8 = fminf(fmaxf(q8, -127.f), 127.f);
  const float scale = (q8 / 127.f) * sa;
  const float safe_am = (amax == 0.f) ? 1.f : amax;

  auto dq1 = [&](float x) -> unsigned short {
    const float norm = x / safe_am;
    int idx = 0;
#pragma unroll
    for (int j = 0; j < 15; ++j) idx += (NF4_BND[j] < norm) ? 1 : 0;
    return f2bf(s_code[idx] * scale);
  };

  uint4* dst = (uint4*)(wdq + base);
#pragma unroll
  for (int i = 0; i < 8; ++i) {
    const f32x4 a = v[2 * i], b = v[2 * i + 1];
    uint4 o;
    o.x = (unsigned)dq1(a[0]) | ((unsigned)dq1(a[1]) << 16);
    o.y = (unsigned)dq1(a[2]) | ((unsigned)dq1(a[3]) << 16);
    o.z = (unsigned)dq1(b[0]) | ((unsigned)dq1(b[1]) << 16);
    o.w = (unsigned)dq1(b[2]) | ((unsigned)dq1(b[3]) << 16);
    dst[i] = o;
  }
}

// ---------------------------------------------------------------------------
// Kernel 2: cast x fp32 -> bf16 bits (grid-stride, nt loads of x)
// ---------------------------------------------------------------------------
__global__ __launch_bounds__(256) void cast_f32_to_bf16(const float* __restrict__ x,
                                                        unsigned short* __restrict__ y,
                                                        size_t n8) {
  const size_t stride = (size_t)gridDim.x * 256;
  for (size_t i = (size_t)blockIdx.x * 256 + threadIdx.x; i < n8; i += stride) {
    const f32x4* s = (const f32x4*)x + i * 2;
    const f32x4 a = __builtin_nontemporal_load(s);
    const f32x4 b = __builtin_nontemporal_load(s + 1);
    uint4 o;
    o.x = (unsigned)f2bf(a[0]) | ((unsigned)f2bf(a[1]) << 16);
    o.y = (unsigned)f2bf(a[2]) | ((unsigned)f2bf(a[3]) << 16);
    o.z = (unsigned)f2bf(b[0]) | ((unsigned)f2bf(b[1]) << 16);
    o.w = (unsigned)f2bf(b[2]) | ((unsigned)f2bf(b[3]) << 16);
    ((uint4*)y)[i] = o;  // normal store: xbf IS re-read by the GEMM (L3-resident)
  }
}

// ---------------------------------------------------------------------------
// Kernel 3: C[M,N] = A[M,K] * Bt[N,K]^T, bf16 inputs, fp32 out.
// 256x256 tile, BK=64, 512 threads (8 waves = 2Mx4N, each wave 128x64 via
// 8x4 grid of v_mfma_f32_16x16x32_bf16).
//
// 8-phase schedule, 2 K-tiles/iter. Reads spread 12/4/8/0 per 4-phase group
// (A-half regs reused across 2 quadrants; both B-halves held in regs), so
// each LDS half-region is free ONE phase after its read. Stage ring writes
// exactly the region freed last phase -> uniform 4-7 phase stage->read
// distance, protected by vmcnt(6) at P4/P8 only (3 half-tiles always in
// flight; never drains).
//
//   phase | ds_reads (buf)        | stage (1 half = 2 gld16)      | MFMA
//   P1    | A-lo + B-lo (12), b0  | buf1 A-hi  (tile 2it+1, k+64) | (0,0)
//   P2    | B-hi (4), b0          | buf0 B-lo  (tile 2it+2,k+128) | (0,1)
//   P3    | A-hi (8), b0          | buf0 A-lo                     | (1,0)
//   P4    | --                    | buf0 B-hi, vmcnt(6)           | (1,1)
//   P5    | A-lo + B-lo (12), b1  | buf0 A-hi                     | (0,0)
//   P6    | B-hi (4), b1          | buf1 B-lo  (tile 2it+3,k+192) | (0,1)
//   P7    | A-hi (8), b1          | buf1 A-lo                     | (1,0)
//   P8    | --                    | buf1 B-hi, vmcnt(6)           | (1,1)
//
// RAW: vmcnt(6)@P4 leaves only P2/P3/P4 stages outstanding -> everything read
// in P5-P7 (staged prev-P6..this-P1) has landed. vmcnt(6)@P8 leaves P6/P7/P8
// -> buf0 (staged P2-P5) landed before next-P1 reads. WAR: each stage targets
// a region whose reads completed >=1 phase earlier (barrier-ordered).
//
// LDS (128 KiB): [buf(2)][A/B(2)][half(2)][128 rows][64 k] bf16.
// T2 swizzle: slot s at row r holds logical k-chunk s^(r&7); global source
// pre-swizzled (linear LDS dest for global_load_lds), ds_read applies same XOR.
// ---------------------------------------------------------------------------

__device__ __forceinline__ void gld16(const unsigned short* g, unsigned short* l) {
  __builtin_amdgcn_global_load_lds(
      (__attribute__((address_space(1))) void*)g,
      (__attribute__((address_space(3))) void*)l, 16, 0, 0);
}

#define BAR __builtin_amdgcn_s_barrier()
#define LGKM0 asm volatile("s_waitcnt lgkmcnt(0)" ::: "memory")
#define VMW(n) asm volatile("s_waitcnt vmcnt(" #n ")" ::: "memory")

#define STG(buf, ab, hf, ks)                                                   \
  do {                                                                         \
    const unsigned short* g_ =                                                 \
        ((ab) ? gB0 : gA0) + (size_t)(hf)*HOFF + (size_t)(ks);                 \
    unsigned short* l_ =                                                       \
        lds + (buf)*32768 + (ab)*16384 + (hf)*8192 + wvoff;                    \
    gld16(g_, l_);                                                             \
    gld16(g_ + 64 * (size_t)K, l_ + 4096);                                     \
  } while (0)

#define RD_A(buf, mh)                                                          \
  do {                                                                         \
    _Pragma("unroll") for (int i4 = 0; i4 < 4; ++i4) {                         \
      afr[i4][0] = *(const bf16x8*)(pa + (buf)*32768 + (mh)*4096 +             \
                                    i4 * 1024 + aoff0);                        \
      afr[i4][1] = *(const bf16x8*)(pa + (buf)*32768 + (mh)*4096 +             \
                                    i4 * 1024 + aoff1);                        \
    }                                                                          \
  } while (0)

#define RD_B(buf, nh)                                                          \
  do {                                                                         \
    _Pragma("unroll") for (int j2 = 0; j2 < 2; ++j2) {                         \
      bfr[(nh)*2 + j2][0] = *(const bf16x8*)(pb + (buf)*32768 + (nh)*2048 +    \
                                             j2 * 1024 + aoff0);               \
      bfr[(nh)*2 + j2][1] = *(const bf16x8*)(pb + (buf)*32768 + (nh)*2048 +    \
                                             j2 * 1024 + aoff1);               \
    }                                                                          \
  } while (0)

#define MM(mh, nh)                                                             \
  do {                                                                         \
    __builtin_amdgcn_s_setprio(1);                                             \
    _Pragma("unroll") for (int ks = 0; ks < 2; ++ks) {                         \
      _Pragma("unroll") for (int i4 = 0; i4 < 4; ++i4) {                       \
        _Pragma("unroll") for (int j2 = 0; j2 < 2; ++j2) {                     \
          acc[(mh)*4 + i4][(nh)*2 + j2] =                                      \
              __builtin_amdgcn_mfma_f32_16x16x32_bf16(                         \
                  afr[i4][ks], bfr[(nh)*2 + j2][ks],                           \
                  acc[(mh)*4 + i4][(nh)*2 + j2], 0, 0, 0);                     \
        }                                                                      \
      }                                                                        \
    }                                                                          \
    __builtin_amdgcn_s_setprio(0);                                             \
  } while (0)

__global__ __launch_bounds__(512, 2) void gemm8p(const unsigned short* __restrict__ A,
                                                 const unsigned short* __restrict__ Bt,
                                                 float* __restrict__ C,
                                                 int M, int N, int K) {
  __shared__ __align__(16) unsigned short lds[65536];  // 128 KiB

  const int t = threadIdx.x;
  const int wave = t >> 6;
  const int lane = t & 63;

  // --- T1: bijective XCD-aware block swizzle ---
  const int nbx = N >> 8;
  const int nwg = nbx * (M >> 8);
  const int q8 = nwg >> 3, r8 = nwg & 7;
  const int xcd = (int)blockIdx.x & 7, off = (int)blockIdx.x >> 3;
  const int wg =
      (xcd < r8 ? xcd * (q8 + 1) : r8 * (q8 + 1) + (xcd - r8) * q8) + off;
  const int bm = (wg / nbx) << 8;
  const int bn = (wg % nbx) << 8;

  // --- staging addressing (per-lane, source pre-swizzled) ---
  const size_t HOFF = (size_t)128 * K;            // half-tile row offset (elems)
  const int srow = wave * 8 + (lane >> 3);        // local row in [0,64)
  const int sj = (lane & 7) ^ (lane >> 3);        // inverse-swizzled k-chunk
  const unsigned short* gA0 = A + (size_t)(bm + srow) * K + sj * 8;
  const unsigned short* gB0 = Bt + (size_t)(bn + srow) * K + sj * 8;
  const int wvoff = wave * 512;                   // LDS chunk base (elems)

  // --- compute addressing ---
  const int wm = wave >> 2;   // m half owned by this wave (A hf region)
  const int wn = wave & 3;    // n quarter owned by this wave
  const int quad = lane >> 4;
  const int lrow = lane & 15;
  const int s0 = quad ^ (lrow & 7);               // swizzled chunk, ks=0
  const int aoff0 = lrow * 64 + s0 * 8;           // elems within half-region
  const int aoff1 = lrow * 64 + (s0 ^ 4) * 8;     // ks=1
  const unsigned short* pa = lds + wm * 8192;
  const unsigned short* pb = lds + 16384 + (wn >> 1) * 8192 + (wn & 1) * 4096;

  f32x4 acc[8][4];
  const f32x4 zero = {0.f, 0.f, 0.f, 0.f};
#pragma unroll
  for (int i = 0; i < 8; ++i)
#pragma unroll
    for (int j = 0; j < 4; ++j) acc[i][j] = zero;

  bf16x8 afr[4][2];   // current A sub-half (aliased across mh)
  bf16x8 bfr[4][2];   // both B sub-halves

  // --- prologue: tile0 fully -> buf0; tile1 B-lo, A-lo, B-hi -> buf1 ---
  STG(0, 0, 0, 0);   // buf0 A-lo   (oldest 8 loads = all of buf0)
  STG(0, 1, 0, 0);   // buf0 B-lo
  STG(0, 1, 1, 0);   // buf0 B-hi
  STG(0, 0, 1, 0);   // buf0 A-hi
  STG(1, 1, 0, 64);  // buf1 B-lo
  STG(1, 0, 0, 64);  // buf1 A-lo
  STG(1, 1, 1, 64);  // buf1 B-hi
  VMW(6);            // oldest 8 landed -> buf0 complete; buf1 3 halves fly
  BAR;

  const int niter = K >> 7;  // 2 K-tiles (2*BK=128) per iteration
  for (int it = 0; it < niter; ++it) {
    const int kt = it << 7;
    const int kA = kt + 64;                              // tile 2it+1 (real)
    int kB0 = kt + 128; if (kB0 > K - 64) kB0 = K - 64;  // dummy on last iter
    int kB1 = kt + 192; if (kB1 > K - 64) kB1 = K - 64;  // (regions unread)

    // P1
    RD_A(0, 0); RD_B(0, 0); STG(1, 0, 1, kA);
    BAR; LGKM0; MM(0, 0); BAR;
    // P2
    RD_B(0, 1); STG(0, 1, 0, kB0);
    BAR; LGKM0; MM(0, 1); BAR;
    // P3
    RD_A(0, 1); STG(0, 0, 0, kB0);
    BAR; LGKM0; MM(1, 0); BAR;
    // P4
    STG(0, 1, 1, kB0); VMW(6);
    BAR; MM(1, 1); BAR;
    // P5
    RD_A(1, 0); RD_B(1, 0); STG(0, 0, 1, kB0);
    BAR; LGKM0; MM(0, 0); BAR;
    // P6
    RD_B(1, 1); STG(1, 1, 0, kB1);
    BAR; LGKM0; MM(0, 1); BAR;
    // P7
    RD_A(1, 1); STG(1, 0, 0, kB1);
    BAR; LGKM0; MM(1, 0); BAR;
    // P8
    STG(1, 1, 1, kB1); VMW(6);
    BAR; MM(1, 1); BAR;
  }

  // drain LDS-DMA before block exit
  VMW(0);

  // epilogue: D[row=quad*4+r][col=lrow] per 16x16 tile; nontemporal stores
  // (C streams once; keep A/B panels resident in L3 across block rounds)
  const int crow = bm + wm * 128 + quad * 4;
  const int ccol = bn + wn * 64 + lrow;
#pragma unroll
  for (int i = 0; i < 8; ++i) {
#pragma unroll
    for (int j = 0; j < 4; ++j) {
      float* cp = C + (size_t)(crow + i * 16) * N + (ccol + j * 16);
#pragma unroll
      for (int r = 0; r < 4; ++r)
        __builtin_nontemporal_store(acc[i][j][r], cp + (size_t)r * N);
    }
  }
}

// ---------------------------------------------------------------------------
extern "C" void kernel_launch(void* const* d_in, const int* in_sizes, int n_in,
                              void* d_out, int out_size, void* d_ws, size_t ws_size,
                              hipStream_t stream) {
  const float* x = (const float*)d_in[0];   // [M, K]
  const float* w = (const float*)d_in[1];   // [N, K]
  const int K = 4096;
  const int M = in_sizes[0] / K;            // 16384
  const int N = in_sizes[1] / K;            // 4096

  unsigned short* wdq = (unsigned short*)d_ws;            // [N*K] bf16 bits
  unsigned short* xbf = wdq + (size_t)in_sizes[1];        // [M*K] bf16 bits
  // needs ws_size >= 2*(in_sizes[0]+in_sizes[1]) = 168 MB

  nf4_dequant<<<in_sizes[1] / 16384, 256, 0, stream>>>(w, wdq);
  cast_f32_to_bf16<<<4096, 256, 0, stream>>>(x, xbf, (size_t)in_sizes[0] / 8);
  dim3 grid((N / 256) * (M / 256));
  gemm8p<<<grid, 512, 0, stream>>>(xbf, wdq, (float*)d_out, M, N, K);
}

// Round 4
// 863.778 us; speedup vs baseline: 1.3540x; 1.0275x over previous
//
#include <hip/hip_runtime.h>
#include <stdint.h>

// ---------------------------------------------------------------------------
// out = x @ nf4_quant_dequant(w).T
//   x: [M=16384, K=4096] fp32,  w: [N=4096, K=4096] fp32,  out: [M, N] fp32
// Plan: (1) fake-quant w -> bf16 (coalesced, wave-cooperative), (2) cast x ->
//       bf16, (3) bf16 MFMA GEMM 256x256/BK=64/8 waves, 8-phase schedule with
//       a 1-PHASE-AHEAD READ PIPELINE: each phase's MFMA cluster consumes
//       fragments read in the previous phase; reads for the next MM set are
//       interleaved mid-cluster (register WAR gives ordering, zero extra
//       banks). No explicit lgkm drains (compiler emits partial waits).
//       One barrier per phase. vmcnt(8) ring, stage bursts at P2/P3/P6/P7.
// ws usage: w_bf16 (33.5 MB) + x_bf16 (134 MB) = 168 MB.
// ---------------------------------------------------------------------------

typedef __bf16 bf16x8 __attribute__((ext_vector_type(8)));
typedef float f32x4 __attribute__((ext_vector_type(4)));  // native vec (nt-load OK)

constexpr float NF4_CODE[16] = {
    -1.0f, -0.6961928009986877f, -0.5250730514526367f, -0.39491748809814453f,
    -0.28444138169288635f, -0.18477343022823334f, -0.09105003625154495f, 0.0f,
    0.07958029955625534f, 0.16093020141124725f, 0.24611230194568634f,
    0.33791524171829224f, 0.44070982933044434f, 0.5626170039176941f,
    0.7229568362236023f, 1.0f};
constexpr float NF4_BND[15] = {
    0.5f * (NF4_CODE[0] + NF4_CODE[1]),   0.5f * (NF4_CODE[1] + NF4_CODE[2]),
    0.5f * (NF4_CODE[2] + NF4_CODE[3]),   0.5f * (NF4_CODE[3] + NF4_CODE[4]),
    0.5f * (NF4_CODE[4] + NF4_CODE[5]),   0.5f * (NF4_CODE[5] + NF4_CODE[6]),
    0.5f * (NF4_CODE[6] + NF4_CODE[7]),   0.5f * (NF4_CODE[7] + NF4_CODE[8]),
    0.5f * (NF4_CODE[8] + NF4_CODE[9]),   0.5f * (NF4_CODE[9] + NF4_CODE[10]),
    0.5f * (NF4_CODE[10] + NF4_CODE[11]), 0.5f * (NF4_CODE[11] + NF4_CODE[12]),
    0.5f * (NF4_CODE[12] + NF4_CODE[13]), 0.5f * (NF4_CODE[13] + NF4_CODE[14]),
    0.5f * (NF4_CODE[14] + NF4_CODE[15])};

__device__ __forceinline__ unsigned short f2bf(float f) {
  unsigned int u = __float_as_uint(f);
  u += 0x7fffu + ((u >> 16) & 1u);
  return (unsigned short)(u >> 16);
}

// ---------------------------------------------------------------------------
// Kernel 1: NF4 fake quant-dequant, fp32 -> bf16 bits. Fully coalesced:
// block = one scale superblock (16384 floats); round k loads float4 idx
// k*256+t (lane-contiguous); 16 consecutive lanes own one quant block ->
// amax via 16-lane shfl_xor reduce.
// ---------------------------------------------------------------------------
__global__ __launch_bounds__(256) void nf4_dequant(const float* __restrict__ w,
                                                   unsigned short* __restrict__ wdq) {
  __shared__ float s_am[256];
  __shared__ float s_red[4];
  __shared__ float s_code[16];
  const int t = threadIdx.x;
  if (t < 16) s_code[t] = NF4_CODE[t];
  const size_t base = (size_t)blockIdx.x * 16384;
  const f32x4* src = (const f32x4*)(w + base);

  f32x4 v[16];
#pragma unroll
  for (int k = 0; k < 16; ++k) {
    v[k] = __builtin_nontemporal_load(src + k * 256 + t);
    float m = fmaxf(fmaxf(fabsf(v[k][0]), fabsf(v[k][1])),
                    fmaxf(fabsf(v[k][2]), fabsf(v[k][3])));
    m = fmaxf(m, __shfl_xor(m, 1));
    m = fmaxf(m, __shfl_xor(m, 2));
    m = fmaxf(m, __shfl_xor(m, 4));
    m = fmaxf(m, __shfl_xor(m, 8));
    if ((t & 15) == 0) s_am[k * 16 + (t >> 4)] = m;  // quant block id
  }
  __syncthreads();
  // superblock absmax = max over the 256 block scales
  float m = s_am[t];
  m = fmaxf(m, __shfl_xor(m, 1));
  m = fmaxf(m, __shfl_xor(m, 2));
  m = fmaxf(m, __shfl_xor(m, 4));
  m = fmaxf(m, __shfl_xor(m, 8));
  m = fmaxf(m, __shfl_xor(m, 16));
  m = fmaxf(m, __shfl_xor(m, 32));
  if ((t & 63) == 0) s_red[t >> 6] = m;
  __syncthreads();
  const float s_amax = fmaxf(fmaxf(s_red[0], s_red[1]), fmaxf(s_red[2], s_red[3]));
  const float sa = (s_amax == 0.f) ? 1.f : s_amax;

#pragma unroll
  for (int k = 0; k < 16; ++k) {
    const float am = s_am[k * 16 + (t >> 4)];
    float q8 = rintf(am / sa * 127.f);
    q8 = fminf(fmaxf(q8, -127.f), 127.f);
    const float scale = (q8 / 127.f) * sa;
    const float safe_am = (am == 0.f) ? 1.f : am;
    unsigned r[4];
#pragma unroll
    for (int e = 0; e < 4; ++e) {
      const float norm = v[k][e] / safe_am;
      int idx = 0;
#pragma unroll
      for (int j = 0; j < 15; ++j) idx += (NF4_BND[j] < norm) ? 1 : 0;
      r[e] = (unsigned)f2bf(s_code[idx] * scale);
    }
    uint2 o;
    o.x = r[0] | (r[1] << 16);
    o.y = r[2] | (r[3] << 16);
    ((uint2*)(wdq + base))[k * 256 + t] = o;
  }
}

// ---------------------------------------------------------------------------
// Kernel 2: cast x fp32 -> bf16 bits (grid-stride, nt loads of x)
// ---------------------------------------------------------------------------
__global__ __launch_bounds__(256) void cast_f32_to_bf16(const float* __restrict__ x,
                                                        unsigned short* __restrict__ y,
                                                        size_t n8) {
  const size_t stride = (size_t)gridDim.x * 256;
  for (size_t i = (size_t)blockIdx.x * 256 + threadIdx.x; i < n8; i += stride) {
    const f32x4* s = (const f32x4*)x + i * 2;
    const f32x4 a = __builtin_nontemporal_load(s);
    const f32x4 b = __builtin_nontemporal_load(s + 1);
    uint4 o;
    o.x = (unsigned)f2bf(a[0]) | ((unsigned)f2bf(a[1]) << 16);
    o.y = (unsigned)f2bf(a[2]) | ((unsigned)f2bf(a[3]) << 16);
    o.z = (unsigned)f2bf(b[0]) | ((unsigned)f2bf(b[1]) << 16);
    o.w = (unsigned)f2bf(b[2]) | ((unsigned)f2bf(b[3]) << 16);
    ((uint4*)y)[i] = o;  // xbf IS re-read by the GEMM (L3-resident)
  }
}

// ---------------------------------------------------------------------------
// Kernel 3: C[M,N] = A[M,K] * Bt[N,K]^T, bf16 in, fp32 out.
// 256x256 tile, BK=64, 512 thr (8 waves = 2Mx4N, wave = 128x64 via 8x4 of
// 16x16x32 MFMA). 8 phases / 2 K-tiles per iter.
//
// READ PIPELINE (1 phase ahead, zero extra frag banks):
//   phase | MM set (tile) | interleaved RD (next set)  | stage (4x gld16)
//   P1    | (lo,lo) T0    | B-hi(T0)  [4]              | --
//   P2    | (lo,hi) T0    | A-hi(T0)  [8]              | B(T2) both halves
//   P3    | (hi,lo) T0    | B-lo(T1)  [4]              | A(T2) both halves
//   P4    | (hi,hi) T0    | A-lo(T1)  [8]              | --
//   P5-P8 mirror for T1 / T3 / reads of T2 into buf0.
// Each phase: { vmcnt(8); stage; barrier; setprio1; MM(ks0); RD(ks0);
//               MM(ks1); RD(ks1); setprio0 }.
// - MM's operands were read >=1 full phase earlier -> ds latency hidden;
//   compiler places partial lgkm waits (no explicit drains).
// - RD(ksX) overwrites exactly the regs MM(ksX) just consumed (register WAR
//   orders them; interleave keeps the other ks half intact).
// - ONE barrier per phase. vmcnt(8) keeps 8 gld16 (2 half-regions) in
//   flight; stage->read distance is 5 phases everywhere; VMW+barrier makes
//   the per-wave vmcnt guarantee cross-wave.
// - WAR on LDS regions: a region is re-staged >=1 barrier after its last
//   ds_read issues, and the DMA write lands ~900cy after issue.
//
// LDS (128 KiB): [buf(2)][A/B(2)][half(2)][128 rows][64 k] bf16, T2 swizzle
// (slot s at row r holds k-chunk s^(r&7); pre-swizzled global source, same
// XOR on ds_read).
// ---------------------------------------------------------------------------

__device__ __forceinline__ void gld16(const unsigned short* g, unsigned short* l) {
  __builtin_amdgcn_global_load_lds(
      (__attribute__((address_space(1))) void*)g,
      (__attribute__((address_space(3))) void*)l, 16, 0, 0);
}

#define BARX                                                                   \
  do {                                                                         \
    asm volatile("" ::: "memory");                                             \
    __builtin_amdgcn_s_barrier();                                              \
    asm volatile("" ::: "memory");                                             \
  } while (0)
#define VMW(n) asm volatile("s_waitcnt vmcnt(" #n ")" ::: "memory")
#define SP1 __builtin_amdgcn_s_setprio(1)
#define SP0 __builtin_amdgcn_s_setprio(0)

#define STG(buf, ab, hf, ks)                                                   \
  do {                                                                         \
    const unsigned short* g_ =                                                 \
        ((ab) ? gB0 : gA0) + (size_t)(hf)*HOFF + (size_t)(ks);                 \
    unsigned short* l_ =                                                       \
        lds + (buf)*32768 + (ab)*16384 + (hf)*8192 + wvoff;                    \
    gld16(g_, l_);                                                             \
    gld16(g_ + 64 * (size_t)K, l_ + 4096);                                     \
  } while (0)

#define RDA(buf, mh, ks)                                                       \
  do {                                                                         \
    _Pragma("unroll") for (int i4 = 0; i4 < 4; ++i4) {                         \
      afr[i4][ks] = *(const bf16x8*)(pa + (buf)*32768 + (mh)*4096 +            \
                                     i4 * 1024 + ((ks) ? aoff1 : aoff0));      \
    }                                                                          \
  } while (0)

#define RDB(buf, nh, ks)                                                       \
  do {                                                                         \
    _Pragma("unroll") for (int j2 = 0; j2 < 2; ++j2) {                         \
      bfr[(nh)*2 + j2][ks] = *(const bf16x8*)(pb + (buf)*32768 + (nh)*2048 +   \
                                              j2 * 1024 +                      \
                                              ((ks) ? aoff1 : aoff0));         \
    }                                                                          \
  } while (0)

#define MMH(mh, nh, ks)                                                        \
  do {                                                                         \
    _Pragma("unroll") for (int i4 = 0; i4 < 4; ++i4) {                         \
      _Pragma("unroll") for (int j2 = 0; j2 < 2; ++j2) {                       \
        acc[(mh)*4 + i4][(nh)*2 + j2] =                                        \
            __builtin_amdgcn_mfma_f32_16x16x32_bf16(                           \
                afr[i4][ks], bfr[(nh)*2 + j2][ks],                             \
                acc[(mh)*4 + i4][(nh)*2 + j2], 0, 0, 0);                       \
      }                                                                        \
    }                                                                          \
  } while (0)

__global__ __launch_bounds__(512, 2) void gemm8p(const unsigned short* __restrict__ A,
                                                 const unsigned short* __restrict__ Bt,
                                                 float* __restrict__ C,
                                                 int M, int N, int K) {
  __shared__ __align__(16) unsigned short lds[65536];  // 128 KiB

  const int t = threadIdx.x;
  const int wave = t >> 6;
  const int lane = t & 63;

  // --- T1: bijective XCD-aware block swizzle ---
  const int nbx = N >> 8;
  const int nwg = nbx * (M >> 8);
  const int q8 = nwg >> 3, r8 = nwg & 7;
  const int xcd = (int)blockIdx.x & 7, off = (int)blockIdx.x >> 3;
  const int wg =
      (xcd < r8 ? xcd * (q8 + 1) : r8 * (q8 + 1) + (xcd - r8) * q8) + off;
  const int bm = (wg / nbx) << 8;
  const int bn = (wg % nbx) << 8;

  // --- staging addressing (per-lane, source pre-swizzled) ---
  const size_t HOFF = (size_t)128 * K;            // half-tile row offset (elems)
  const int srow = wave * 8 + (lane >> 3);        // local row in [0,64)
  const int sj = (lane & 7) ^ (lane >> 3);        // inverse-swizzled k-chunk
  const unsigned short* gA0 = A + (size_t)(bm + srow) * K + sj * 8;
  const unsigned short* gB0 = Bt + (size_t)(bn + srow) * K + sj * 8;
  const int wvoff = wave * 512;                   // LDS chunk base (elems)

  // --- compute addressing ---
  const int wm = wave >> 2;   // m half owned by this wave
  const int wn = wave & 3;    // n quarter owned by this wave
  const int quad = lane >> 4;
  const int lrow = lane & 15;
  const int s0 = quad ^ (lrow & 7);               // swizzled chunk, ks=0
  const int aoff0 = lrow * 64 + s0 * 8;
  const int aoff1 = lrow * 64 + (s0 ^ 4) * 8;     // ks=1
  const unsigned short* pa = lds + wm * 8192;
  const unsigned short* pb = lds + 16384 + (wn >> 1) * 8192 + (wn & 1) * 4096;

  f32x4 acc[8][4];
  const f32x4 zero = {0.f, 0.f, 0.f, 0.f};
#pragma unroll
  for (int i = 0; i < 8; ++i)
#pragma unroll
    for (int j = 0; j < 4; ++j) acc[i][j] = zero;

  bf16x8 afr[4][2];   // current A sub-half (rotates lo->hi->lo' ...)
  bf16x8 bfr[4][2];   // [0..1]=B-lo, [2..3]=B-hi of current tile

  // --- prologue: stage B(T0),A(T0),B(T1),A(T1); prime A-lo/B-lo(T0) ---
  STG(0, 1, 0, 0); STG(0, 1, 1, 0);   // B(T0)
  STG(0, 0, 0, 0); STG(0, 0, 1, 0);   // A(T0)
  STG(1, 1, 0, 64); STG(1, 1, 1, 64); // B(T1)
  STG(1, 0, 0, 64); STG(1, 0, 1, 64); // A(T1)
  VMW(8);  // B(T0)+A(T0) landed (oldest 8); B(T1)+A(T1) in flight
  BARX;
  RDA(0, 0, 0); RDA(0, 0, 1);  // prime afr = A-lo(T0)
  RDB(0, 0, 0); RDB(0, 0, 1);  // prime bfr[0..1] = B-lo(T0)

  const int niter = K >> 7;  // 2 K-tiles per iteration
  for (int it = 0; it < niter; ++it) {
    const int kt = it << 7;
    int kc2 = kt + 128; if (kc2 > K - 64) kc2 = K - 64;  // T2 (dummy on tail)
    int kc3 = kt + 192; if (kc3 > K - 64) kc3 = K - 64;  // T3

    // P1: MM(lo,lo) T0 | RD B-hi(T0)
    VMW(8); BARX;
    SP1; MMH(0, 0, 0); RDB(0, 1, 0); MMH(0, 0, 1); RDB(0, 1, 1); SP0;
    // P2: MM(lo,hi) T0 | RD A-hi(T0) | stage B(T2)
    VMW(8); STG(0, 1, 0, kc2); STG(0, 1, 1, kc2); BARX;
    SP1; MMH(0, 1, 0); RDA(0, 1, 0); MMH(0, 1, 1); RDA(0, 1, 1); SP0;
    // P3: MM(hi,lo) T0 | RD B-lo(T1) | stage A(T2)
    VMW(8); STG(0, 0, 0, kc2); STG(0, 0, 1, kc2); BARX;
    SP1; MMH(1, 0, 0); RDB(1, 0, 0); MMH(1, 0, 1); RDB(1, 0, 1); SP0;
    // P4: MM(hi,hi) T0 | RD A-lo(T1)
    VMW(8); BARX;
    SP1; MMH(1, 1, 0); RDA(1, 0, 0); MMH(1, 1, 1); RDA(1, 0, 1); SP0;
    // P5: MM(lo,lo) T1 | RD B-hi(T1)
    VMW(8); BARX;
    SP1; MMH(0, 0, 0); RDB(1, 1, 0); MMH(0, 0, 1); RDB(1, 1, 1); SP0;
    // P6: MM(lo,hi) T1 | RD A-hi(T1) | stage B(T3)
    VMW(8); STG(1, 1, 0, kc3); STG(1, 1, 1, kc3); BARX;
    SP1; MMH(0, 1, 0); RDA(1, 1, 0); MMH(0, 1, 1); RDA(1, 1, 1); SP0;
    // P7: MM(hi,lo) T1 | RD B-lo(T2) | stage A(T3)
    VMW(8); STG(1, 0, 0, kc3); STG(1, 0, 1, kc3); BARX;
    SP1; MMH(1, 0, 0); RDB(0, 0, 0); MMH(1, 0, 1); RDB(0, 0, 1); SP0;
    // P8: MM(hi,hi) T1 | RD A-lo(T2)
    VMW(8); BARX;
    SP1; MMH(1, 1, 0); RDA(0, 0, 0); MMH(1, 1, 1); RDA(0, 0, 1); SP0;
  }

  // drain LDS-DMA before epilogue
  VMW(0);

  // epilogue: D[row=quad*4+r][col=lrow] per 16x16 tile; nontemporal stores
  const int crow = bm + wm * 128 + quad * 4;
  const int ccol = bn + wn * 64 + lrow;
#pragma unroll
  for (int i = 0; i < 8; ++i) {
#pragma unroll
    for (int j = 0; j < 4; ++j) {
      float* cp = C + (size_t)(crow + i * 16) * N + (ccol + j * 16);
#pragma unroll
      for (int r = 0; r < 4; ++r)
        __builtin_nontemporal_store(acc[i][j][r], cp + (size_t)r * N);
    }
  }
}

// ---------------------------------------------------------------------------
extern "C" void kernel_launch(void* const* d_in, const int* in_sizes, int n_in,
                              void* d_out, int out_size, void* d_ws, size_t ws_size,
                              hipStream_t stream) {
  const float* x = (const float*)d_in[0];   // [M, K]
  const float* w = (const float*)d_in[1];   // [N, K]
  const int K = 4096;
  const int M = in_sizes[0] / K;            // 16384
  const int N = in_sizes[1] / K;            // 4096

  unsigned short* wdq = (unsigned short*)d_ws;            // [N*K] bf16 bits
  unsigned short* xbf = wdq + (size_t)in_sizes[1];        // [M*K] bf16 bits
  // needs ws_size >= 2*(in_sizes[0]+in_sizes[1]) = 168 MB

  nf4_dequant<<<in_sizes[1] / 16384, 256, 0, stream>>>(w, wdq);
  cast_f32_to_bf16<<<4096, 256, 0, stream>>>(x, xbf, (size_t)in_sizes[0] / 8);
  dim3 grid((N / 256) * (M / 256));
  gemm8p<<<grid, 512, 0, stream>>>(xbf, wdq, (float*)d_out, M, N, K);
}